// Round 5
// baseline (189.666 us; speedup 1.0000x reference)
//
#include <hip/hip_runtime.h>
#include <cstdint>

// ExcitationShaper: segment-averaged params -> sigmoid/logspace maps -> gain ->
// fractional pluck comb -> time-varying RBJ low-pass biquad (TDF-II).
// Single fused compose+scan+apply kernel with ticket-ordered decoupled
// look-back across the 16 parts of each row (agent-scope atomics; dual
// agg/pref slots so payloads are never overwritten). Comb gathers from a
// padded LDS tile; per-sample coefs cached in VGPRs between phases.

namespace {
constexpr int B = 32;
constexpr int T = 65536;
constexpr int MAXSEG = 2048;      // >> expected ~66 onsets/row (p=1e-3)
constexpr int WV = 64;            // onset-count waves per row
constexpr int SPAN = T / WV;      // 1024 samples per wave
constexpr int SB = 4096;          // samples per fused block
constexpr int HALO = 256;         // > max comb lag (p < 200 -> lag <= 201)
constexpr int PARTS = T / SB;     // 16 parts per row
constexpr int NB = B * PARTS;     // 512 fused blocks

constexpr float MIN_W_C  = 0.00785398163397448279f; // 2*pi*20/16000 = pi/400
constexpr float LOG2_400 = 8.64385618977472436f;    // log2(pi / MIN_W)
constexpr float LOG2_20  = 4.32192809488736235f;    // log2(2.0/0.1)

__device__ __forceinline__ float sigmoid_precise(float v) {
  return 1.0f / (1.0f + expf(-v));
}
__device__ __forceinline__ int pad16(int i) { return i + (i >> 4); }

// Affine transform s' = M s + d
struct Xf { float m00, m01, m10, m11, d0, d1; };
__device__ __forceinline__ Xf xf_comp(const Xf& l, const Xf& e) {  // e first, then l
  Xf r;
  r.m00 = fmaf(l.m00, e.m00, l.m01 * e.m10);
  r.m01 = fmaf(l.m00, e.m01, l.m01 * e.m11);
  r.m10 = fmaf(l.m10, e.m00, l.m11 * e.m10);
  r.m11 = fmaf(l.m10, e.m01, l.m11 * e.m11);
  r.d0  = fmaf(l.m00, e.d0, fmaf(l.m01, e.d1, l.d0));
  r.d1  = fmaf(l.m10, e.d0, fmaf(l.m11, e.d1, l.d1));
  return r;
}
__device__ __forceinline__ void xf_store(float* p, const Xf& v) {
  __hip_atomic_store(&p[0], v.m00, __ATOMIC_RELAXED, __HIP_MEMORY_SCOPE_AGENT);
  __hip_atomic_store(&p[1], v.m01, __ATOMIC_RELAXED, __HIP_MEMORY_SCOPE_AGENT);
  __hip_atomic_store(&p[2], v.m10, __ATOMIC_RELAXED, __HIP_MEMORY_SCOPE_AGENT);
  __hip_atomic_store(&p[3], v.m11, __ATOMIC_RELAXED, __HIP_MEMORY_SCOPE_AGENT);
  __hip_atomic_store(&p[4], v.d0,  __ATOMIC_RELAXED, __HIP_MEMORY_SCOPE_AGENT);
  __hip_atomic_store(&p[5], v.d1,  __ATOMIC_RELAXED, __HIP_MEMORY_SCOPE_AGENT);
}
__device__ __forceinline__ Xf xf_load(const float* p) {
  Xf v;
  v.m00 = __hip_atomic_load(&p[0], __ATOMIC_RELAXED, __HIP_MEMORY_SCOPE_AGENT);
  v.m01 = __hip_atomic_load(&p[1], __ATOMIC_RELAXED, __HIP_MEMORY_SCOPE_AGENT);
  v.m10 = __hip_atomic_load(&p[2], __ATOMIC_RELAXED, __HIP_MEMORY_SCOPE_AGENT);
  v.m11 = __hip_atomic_load(&p[3], __ATOMIC_RELAXED, __HIP_MEMORY_SCOPE_AGENT);
  v.d0  = __hip_atomic_load(&p[4], __ATOMIC_RELAXED, __HIP_MEMORY_SCOPE_AGENT);
  v.d1  = __hip_atomic_load(&p[5], __ATOMIC_RELAXED, __HIP_MEMORY_SCOPE_AGENT);
  return v;
}
} // namespace

// ---- K1: count onsets per (row, wave-span); also init look-back state ----
__global__ void k_count(const int* __restrict__ onsets, int* __restrict__ cnt,
                        int* __restrict__ aggF, int* __restrict__ prefF,
                        int* __restrict__ ticket) {
  if (threadIdx.x == 0) {
    aggF[blockIdx.x] = 0;
    prefF[blockIdx.x] = 0;
    if (blockIdx.x == 0) *ticket = 0;
  }
  int gw = (blockIdx.x * blockDim.x + threadIdx.x) >> 6;
  int lane = threadIdx.x & 63;
  int b = gw / WV, wv = gw % WV;
  const int4* po = (const int4*)(onsets + b * T + wv * SPAN);
  int run = 0;
  for (int it = 0; it < SPAN / 256; ++it) {     // 4 iters, 16B/lane coalesced
    int4 v = po[it * 64 + lane];
    run += (v.x != 0) + (v.y != 0) + (v.z != 0) + (v.w != 0);
  }
  for (int off = 32; off; off >>= 1) run += __shfl_down(run, off);
  if (lane == 0) cnt[b * WV + wv] = run;
}

// ---- K2: seg ids (u16) + onset positions; span base via in-wave butterfly ----
__global__ void k_segids(const int* __restrict__ onsets, const int* __restrict__ cnt,
                         unsigned short* __restrict__ seg_ids, int* __restrict__ onsetPos) {
  int gw = (blockIdx.x * blockDim.x + threadIdx.x) >> 6;
  int lane = threadIdx.x & 63;
  int b = gw / WV, wv = gw % WV;
  const int rb = b * T;
  int t0 = wv * SPAN;
  // base = sum of counts of spans 0..wv-1 (cnt is tiny -> L2-hot)
  int cl = (lane < wv) ? cnt[b * WV + lane] : 0;
  for (int off = 1; off < 64; off <<= 1) cl += __shfl_xor(cl, off);
  int run = cl;
  unsigned long long bm = (1ull << lane) - 1ull;
  for (int it = 0; it < SPAN / 64; ++it) {
    int t = t0 + it * 64 + lane;
    int o = onsets[rb + t] != 0;
    unsigned long long m = __ballot(o);
    int sid = run + __popcll(m & bm) + o;   // inclusive cumsum
    seg_ids[rb + t] = (unsigned short)min(sid, MAXSEG - 1);
    if (o && sid <= MAXSEG) onsetPos[b * MAXSEG + sid - 1] = t;
    run += __popcll(m);
  }
}

// ---- K3: per-segment average + full coefficient precompute (precise math) ----
__global__ void k_segavg(const float* __restrict__ params, const int* __restrict__ onsetPos,
                         const int* __restrict__ cnt, float4* __restrict__ segc,
                         float* __restrict__ segd) {
  __shared__ float part[4][4];
  __shared__ int s_n;
  int b = blockIdx.x >> 6;   // 64 blocks grid-stride over segments per row
  int s0 = blockIdx.x & 63;
  int tid = threadIdx.x;
  if (tid < 64) {            // nseg = total onsets in row
    int v = cnt[b * WV + tid];
    for (int off = 32; off; off >>= 1) v += __shfl_down(v, off);
    if (tid == 0) s_n = v;
  }
  __syncthreads();
  int n = s_n;
  const float4* pp = (const float4*)params;  // [B][T] float4
  for (int s = s0; s <= n; s += 64) {
    int start = (s == 0) ? 0 : onsetPos[b * MAXSEG + min(s, MAXSEG) - 1];
    int end   = (s == n) ? T : onsetPos[b * MAXSEG + min(s, MAXSEG - 1)];
    float a0 = 0.f, a1 = 0.f, a2 = 0.f, a3 = 0.f;
    for (int t = start + tid; t < end; t += 256) {
      float4 pv = pp[b * T + t];
      a0 += pv.x; a1 += pv.y; a2 += pv.z; a3 += pv.w;
    }
    for (int off = 32; off; off >>= 1) {
      a0 += __shfl_down(a0, off); a1 += __shfl_down(a1, off);
      a2 += __shfl_down(a2, off); a3 += __shfl_down(a3, off);
    }
    if ((tid & 63) == 0) {
      int w = tid >> 6;
      part[w][0] = a0; part[w][1] = a1; part[w][2] = a2; part[w][3] = a3;
    }
    __syncthreads();
    if (tid == 0) {
      float t0 = 0.f, t1 = 0.f, t2 = 0.f, t3 = 0.f;
      for (int w = 0; w < 4; ++w) {
        t0 += part[w][0]; t1 += part[w][1]; t2 += part[w][2]; t3 += part[w][3];
      }
      float inv = 1.0f / (float)max(end - start, 1);
      float av0 = t0 * inv, av1 = t1 * inv, av2 = t2 * inv, av3 = t3 * inv;
      float dist = 0.1f * exp2f(sigmoid_precise(av0) * LOG2_20);
      float wv   = MIN_W_C * exp2f(sigmoid_precise(av1) * LOG2_400);
      float qv   = 0.1f * exp2f(sigmoid_precise(av2) * LOG2_20);
      float mu   = sigmoid_precise(av3);
      float sw = sinf(wv), cw = cosf(wv);
      float alpha = sw / (2.0f * qv);
      float a0c = 1.0f + alpha;
      float b0 = (1.0f - cw) / (2.0f * a0c);
      float na1 = 2.0f * cw / a0c;          // -a1
      float na2 = (alpha - 1.0f) / a0c;     // -a2
      int sl = min(s, MAXSEG - 1);
      segc[b * MAXSEG + sl] = make_float4(mu, b0, na1, na2);
      segd[b * MAXSEG + sl] = dist;
    }
    __syncthreads();
  }
}

// ---- K4: fused compose + row-scan (decoupled look-back) + apply ----
__global__ void __launch_bounds__(256, 2) k_fused(
    const float* __restrict__ f0, const float* __restrict__ x,
    const unsigned short* __restrict__ seg, const float4* __restrict__ segc,
    const float* __restrict__ segd, float* __restrict__ out,
    int* __restrict__ aggF, int* __restrict__ prefF,
    float* __restrict__ aggP, float* __restrict__ prefP,
    int* __restrict__ ticket) {
  __shared__ float s_xd[4624];   // pad16(SB+HALO)
  __shared__ int s_sid[4352];    // pad16(SB)
  __shared__ float wagg[4][6];
  __shared__ float rowpref[2];
  __shared__ int s_tk;
  int tid = threadIdx.x;
  // ticket: guarantees all logical predecessors have started -> no deadlock
  if (tid == 0) s_tk = atomicAdd(ticket, 1);
  __syncthreads();
  int tk = s_tk;
  int b = tk >> 4, part = tk & (PARTS - 1);
  int rb = b * T, rs = b * MAXSEG, bs = part * SB;

  // build tile: xd = x*dist (zero pre-row halo), sid; coalesced, conflict-free
  for (int j = tid; j < SB + HALO; j += 256) {
    int tr = bs - HALO + j;
    float v = 0.f;
    if (tr >= 0) {
      int s = (int)seg[rb + tr];
      v = x[rb + tr] * segd[rs + s];
    }
    s_xd[pad16(j)] = v;
  }
  for (int j = tid; j < SB; j += 256) s_sid[pad16(j)] = (int)seg[rb + bs + j];
  __syncthreads();

  int lane = tid & 63, w = tid >> 6;
  int t0l = tid * 16;
  const float4* f4 = (const float4*)(f0 + rb + bs + t0l);
  float p0c[16], na1c[16], na2c[16];   // cached for apply phase (~48 VGPRs)
  float A00 = 1.f, A01 = 0.f, A10 = 0.f, A11 = 1.f, d0 = 0.f, d1 = 0.f;
#pragma unroll
  for (int k = 0; k < 4; ++k) {
    float4 fv = f4[k];
    float fs[4] = {fv.x, fv.y, fv.z, fv.w};
#pragma unroll
    for (int q = 0; q < 4; ++q) {
      int idx = k * 4 + q;
      int li = t0l + idx;
      int s = s_sid[pad16(li)];
      float4 sc = segc[rs + s];        // {mu, b0, -a1, -a2}
      float p = fs[q] * sc.x;
      float z = floorf(p);
      float alfa = p - z;
      int zi = min((int)z, HALO - 8);  // defensive; p < 200 in practice
      int i1 = li - zi - 1 + HALO;
      float xl1 = s_xd[pad16(i1)];
      float xl2 = s_xd[pad16(i1 - 1)];
      float xc = s_xd[pad16(li + HALO)] - (1.f - alfa) * xl1 - alfa * xl2;
      float p0 = sc.y * xc;
      float na1 = sc.z, na2 = sc.w;
      p0c[idx] = p0; na1c[idx] = na1; na2c[idx] = na2;
      float c0v = p0 * (2.f + na1);
      float c1v = p0 * (1.f + na2);
      float nA00 = fmaf(na1, A00, A10);
      float nA01 = fmaf(na1, A01, A11);
      float nd0  = fmaf(na1, d0, d1 + c0v);
      float nA10 = na2 * A00;
      float nA11 = na2 * A01;
      float nd1  = fmaf(na2, d0, c1v);
      A00 = nA00; A01 = nA01; A10 = nA10; A11 = nA11; d0 = nd0; d1 = nd1;
    }
  }
  // wave-level inclusive Kogge-Stone
#pragma unroll
  for (int off = 1; off < 64; off <<= 1) {
    float P00 = __shfl_up(A00, off), P01 = __shfl_up(A01, off);
    float P10 = __shfl_up(A10, off), P11 = __shfl_up(A11, off);
    float Pd0 = __shfl_up(d0, off),  Pd1 = __shfl_up(d1, off);
    if (lane >= off) {
      float nA00 = fmaf(A00, P00, A01 * P10);
      float nA01 = fmaf(A00, P01, A01 * P11);
      float nA10 = fmaf(A10, P00, A11 * P10);
      float nA11 = fmaf(A10, P01, A11 * P11);
      float nd0  = fmaf(A00, Pd0, fmaf(A01, Pd1, d0));
      float nd1  = fmaf(A10, Pd0, fmaf(A11, Pd1, d1));
      A00 = nA00; A01 = nA01; A10 = nA10; A11 = nA11; d0 = nd0; d1 = nd1;
    }
  }
  if (lane == 63) {
    wagg[w][0] = A00; wagg[w][1] = A01; wagg[w][2] = A10;
    wagg[w][3] = A11; wagg[w][4] = d0;  wagg[w][5] = d1;
  }
  __syncthreads();
  // per-lane exclusive (shift up by 1; lane 0 = identity)
  float E00 = __shfl_up(A00, 1), E01 = __shfl_up(A01, 1);
  float E10 = __shfl_up(A10, 1), E11 = __shfl_up(A11, 1);
  float Ed0 = __shfl_up(d0, 1),  Ed1 = __shfl_up(d1, 1);
  if (lane == 0) { E00 = 1.f; E01 = 0.f; E10 = 0.f; E11 = 1.f; Ed0 = 0.f; Ed1 = 0.f; }
  // exclusive wave prefix P = compose of waves 0..w-1
  float P00 = 1.f, P01 = 0.f, P10 = 0.f, P11 = 1.f, Pd0 = 0.f, Pd1 = 0.f;
  for (int i = 0; i < w; ++i) {
    float W00 = wagg[i][0], W01 = wagg[i][1], W10 = wagg[i][2];
    float W11 = wagg[i][3], Wd0 = wagg[i][4], Wd1 = wagg[i][5];
    float n00 = fmaf(W00, P00, W01 * P10);
    float n01 = fmaf(W00, P01, W01 * P11);
    float n10 = fmaf(W10, P00, W11 * P10);
    float n11 = fmaf(W10, P01, W11 * P11);
    float nd0 = fmaf(W00, Pd0, fmaf(W01, Pd1, Wd0));
    float nd1 = fmaf(W10, Pd0, fmaf(W11, Pd1, Wd1));
    P00 = n00; P01 = n01; P10 = n10; P11 = n11; Pd0 = nd0; Pd1 = nd1;
  }
  // full in-block exclusive X = E after P
  float X00 = fmaf(E00, P00, E01 * P10);
  float X01 = fmaf(E00, P01, E01 * P11);
  float X10 = fmaf(E10, P00, E11 * P10);
  float X11 = fmaf(E10, P01, E11 * P11);
  float Xd0 = fmaf(E00, Pd0, fmaf(E01, Pd1, Ed0));
  float Xd1 = fmaf(E10, Pd0, fmaf(E11, Pd1, Ed1));

  // look-back across parts of this row (thread 0)
  if (tid == 0) {
    Xf G = {wagg[0][0], wagg[0][1], wagg[0][2], wagg[0][3], wagg[0][4], wagg[0][5]};
    for (int i = 1; i < 4; ++i) {
      Xf Wi = {wagg[i][0], wagg[i][1], wagg[i][2], wagg[i][3], wagg[i][4], wagg[i][5]};
      G = xf_comp(Wi, G);              // block aggregate
    }
    if (part == 0) {
      xf_store(prefP + tk * 6, G);
      __hip_atomic_store(&prefF[tk], 1, __ATOMIC_RELEASE, __HIP_MEMORY_SCOPE_AGENT);
      rowpref[0] = 0.f; rowpref[1] = 0.f;
    } else {
      xf_store(aggP + tk * 6, G);      // unblock successors early
      __hip_atomic_store(&aggF[tk], 1, __ATOMIC_RELEASE, __HIP_MEMORY_SCOPE_AGENT);
      Xf R = {1.f, 0.f, 0.f, 1.f, 0.f, 0.f};   // exclusive row prefix
      for (int j = part - 1; j >= 0; --j) {
        int sidx = tk - (part - j);
        bool got_pref = false;
        for (;;) {
          if (__hip_atomic_load(&prefF[sidx], __ATOMIC_ACQUIRE, __HIP_MEMORY_SCOPE_AGENT)) {
            R = xf_comp(R, xf_load(prefP + sidx * 6));
            got_pref = true; break;
          }
          if (__hip_atomic_load(&aggF[sidx], __ATOMIC_ACQUIRE, __HIP_MEMORY_SCOPE_AGENT)) {
            R = xf_comp(R, xf_load(aggP + sidx * 6));
            break;
          }
          __builtin_amdgcn_s_sleep(1);
        }
        if (got_pref) break;
      }
      Xf I = xf_comp(G, R);            // inclusive row prefix through this part
      xf_store(prefP + tk * 6, I);
      __hip_atomic_store(&prefF[tk], 1, __ATOMIC_RELEASE, __HIP_MEMORY_SCOPE_AGENT);
      rowpref[0] = R.d0; rowpref[1] = R.d1;   // state at part start (init=0)
    }
  }
  __syncthreads();
  // chunk-start state for this thread
  float s1 = fmaf(X00, rowpref[0], fmaf(X01, rowpref[1], Xd0));
  float s2 = fmaf(X10, rowpref[0], fmaf(X11, rowpref[1], Xd1));
  // apply phase from cached coefs
  float4* o4 = (float4*)(out + rb + bs + t0l);
#pragma unroll
  for (int k = 0; k < 4; ++k) {
    float ys[4];
#pragma unroll
    for (int q = 0; q < 4; ++q) {
      int idx = k * 4 + q;
      float p0 = p0c[idx];
      float y = p0 + s1;
      ys[q] = y;
      float ns1 = fmaf(na1c[idx], y, fmaf(2.f, p0, s2));
      float ns2 = fmaf(na2c[idx], y, p0);
      s1 = ns1; s2 = ns2;
    }
    o4[k] = make_float4(ys[0], ys[1], ys[2], ys[3]);
  }
}

extern "C" void kernel_launch(void* const* d_in, const int* in_sizes, int n_in,
                              void* d_out, int out_size, void* d_ws, size_t ws_size,
                              hipStream_t stream) {
  const float* f0     = (const float*)d_in[0];
  const float* x      = (const float*)d_in[1];
  const float* params = (const float*)d_in[2];
  const int*   onsets = (const int*)d_in[3];
  float* out = (float*)d_out;

  char* w = (char*)d_ws;
  auto alloc = [&](size_t bytes) -> void* {
    void* p = (void*)w;
    w += (bytes + 255) & ~(size_t)255;
    return p;
  };
  unsigned short* seg_ids = (unsigned short*)alloc(sizeof(unsigned short) * B * T);
  int*    cnt      = (int*)alloc(sizeof(int) * B * WV);
  int*    onsetPos = (int*)alloc(sizeof(int) * B * MAXSEG);
  float4* segc     = (float4*)alloc(sizeof(float4) * B * MAXSEG);
  float*  segd     = (float*)alloc(sizeof(float) * B * MAXSEG);
  int*    aggF     = (int*)alloc(sizeof(int) * NB);
  int*    prefF    = (int*)alloc(sizeof(int) * NB);
  float*  aggP     = (float*)alloc(sizeof(float) * 6 * NB);
  float*  prefP    = (float*)alloc(sizeof(float) * 6 * NB);
  int*    ticket   = (int*)alloc(sizeof(int));
  (void)in_sizes; (void)n_in; (void)out_size; (void)ws_size;

  k_count <<<NB, 256, 0, stream>>>(onsets, cnt, aggF, prefF, ticket);
  k_segids<<<NB, 256, 0, stream>>>(onsets, cnt, seg_ids, onsetPos);
  k_segavg<<<B * 64, 256, 0, stream>>>(params, onsetPos, cnt, segc, segd);
  k_fused <<<NB, 256, 0, stream>>>(f0, x, seg_ids, segc, segd, out,
                                   aggF, prefF, aggP, prefP, ticket);
}